// Round 3
// baseline (354.321 us; speedup 1.0000x reference)
//
#include <hip/hip_runtime.h>
#include <hip/hip_fp16.h>
#include <math.h>

#define NN 4096
#define FIN 20
#define NH 4
#define DH 64
#define ALPHA 0.2f
#define LOG2E 1.4426950408889634f

typedef _Float16 f16x8 __attribute__((ext_vector_type(8)));
typedef _Float16 f16x4 __attribute__((ext_vector_type(4)));
typedef float f32x4 __attribute__((ext_vector_type(4)));

__device__ inline void atomicMaxF(float* a, float v) {
    if (v >= 0.f) atomicMax((int*)a, __float_as_int(v));
    else atomicMin((unsigned int*)a, __float_as_uint(v));
}

// ---- pack adjacency into bitmask + init fdm ----
__global__ void k_pack(const int* __restrict__ adj, unsigned int* __restrict__ bits,
                       float* __restrict__ fdm) {
    int t = blockIdx.x * blockDim.x + threadIdx.x;
    if (blockIdx.x == 0 && threadIdx.x < 16) fdm[threadIdx.x] = -3e38f;
    int pred = adj[t] > 0;
    unsigned long long m = __ballot(pred);
    if ((threadIdx.x & 63) == 0) {
        int w = t >> 5;
        bits[w]     = (unsigned int)m;
        bits[w + 1] = (unsigned int)(m >> 32);
    }
}

// ---- layer0 Wh -> whT (f16, [h][d][n]) + fused fs/fd/fdmax ----
__global__ __launch_bounds__(256) void k_l0wh(const float* __restrict__ x,
        const float* __restrict__ W0, const float* __restrict__ a0,
        _Float16* __restrict__ whT, float* __restrict__ fs, float* __restrict__ fd,
        float* __restrict__ fdm) {
    __shared__ float xs[16 * FIN];
    int n0 = blockIdx.x * 16;
    int tid = threadIdx.x;
    for (int i = tid; i < 16 * FIN; i += 256) xs[i] = x[n0 * FIN + i];
    __syncthreads();
    int h = tid >> 6, d = tid & 63;
    float w0r[FIN];
#pragma unroll
    for (int f = 0; f < FIN; ++f) w0r[f] = W0[(h * FIN + f) * DH + d];
    float asrc = a0[h * 2 * DH + d];
    float adst = a0[h * 2 * DH + DH + d];
    float mdv = -3e38f;
    f16x8 wv[2];
#pragma unroll
    for (int n = 0; n < 16; ++n) {
        float wh = 0.f;
#pragma unroll
        for (int f = 0; f < FIN; ++f) wh = fmaf(xs[n * FIN + f], w0r[f], wh);
        wv[n >> 3][n & 7] = (_Float16)wh;
        float sv = wh * asrc, dv = wh * adst;
#pragma unroll
        for (int off = 1; off <= 32; off <<= 1) {
            sv += __shfl_xor(sv, off);
            dv += __shfl_xor(dv, off);
        }
        mdv = fmaxf(mdv, dv);
        if (d == 0) { fs[h * NN + n0 + n] = sv; fd[h * NN + n0 + n] = dv; }
    }
    if (d == 0) atomicMaxF(fdm + h, mdv);
    _Float16* dst = whT + ((size_t)(h * DH + d) * NN + n0);
    *(f16x8*)(dst) = wv[0];
    *(f16x8*)(dst + 8) = wv[1];
}

// ---- W1 [h][256][64] -> w1T [h][64][256] f16 (read-coalesced) ----
__global__ void k_w1t(const float* __restrict__ W1, _Float16* __restrict__ w1T) {
    int u = blockIdx.x * 256 + threadIdx.x;     // 0..65535
    int h = u >> 14, f = (u >> 6) & 255, d = u & 63;
    w1T[((size_t)(h * DH + d) << 8) + f] = (_Float16)W1[u];
}

// ---- attention: 16 waves, 256-col chunks, 2 row-tiles/wave, LDS reduce ----
// MODE 0: write h16 [n][H*DH] f16   MODE 1: write out1 [h][n][DH] f32
template<int MODE>
__global__ __launch_bounds__(1024, 8) void k_attn(const float* __restrict__ fs,
        const float* __restrict__ fd, const float* __restrict__ fdmax,
        const _Float16* __restrict__ whT, const unsigned int* __restrict__ bits,
        void* __restrict__ outp) {
    __shared__ float red[16][16][64];
    __shared__ float lred[16][16];
    int h = blockIdx.x >> 7;
    int row0 = (blockIdx.x & 127) << 5;         // 32 rows per block
    int tid = threadIdx.x;
    int l = tid & 63, w = tid >> 6;             // w in [0,16)
    int rl = l & 15, g = l >> 4;
    int r0 = row0 + rl, r1 = row0 + 16 + rl;
    float fsr0 = fs[h * NN + r0], fsr1 = fs[h * NN + r1];
    float fm = fdmax[h];
    float s0u = fsr0 + fm, s1u = fsr1 + fm;
    float m0 = fmaxf(s0u, ALPHA * s0u);         // upper bound of row max
    float m1 = fmaxf(s1u, ALPHA * s1u);
    float A0 = (fsr0 - m0) * LOG2E, B0 = (ALPHA * fsr0 - m0) * LOG2E;
    float A1 = (fsr1 - m1) * LOG2E, B1 = (ALPHA * fsr1 - m1) * LOG2E;
    const float* fdp = fd + h * NN;
    const unsigned char* br0 = (const unsigned char*)bits + (size_t)r0 * (NN / 8);
    const unsigned char* br1 = (const unsigned char*)bits + (size_t)r1 * (NN / 8);
    const _Float16* whb = whT + (size_t)h * DH * NN;
    f32x4 a0[4] = {{0,0,0,0},{0,0,0,0},{0,0,0,0},{0,0,0,0}};
    f32x4 a1[4] = {{0,0,0,0},{0,0,0,0},{0,0,0,0},{0,0,0,0}};
    f32x4 al0 = {0,0,0,0}, al1 = {0,0,0,0};
    f16x8 ones;
#pragma unroll
    for (int i = 0; i < 8; ++i) ones[i] = (_Float16)1.0f;
    int c0 = w << 8;                            // 256 cols per wave
    for (int j0 = c0; j0 < c0 + 256; j0 += 32) {
        int jb = j0 + 8 * g;
        float4 fa = *(const float4*)(fdp + jb);
        float4 fb = *(const float4*)(fdp + jb + 4);
        unsigned int mb0 = br0[jb >> 3], mb1 = br1[jb >> 3];
        float fv[8] = {fa.x, fa.y, fa.z, fa.w, fb.x, fb.y, fb.z, fb.w};
        float c1[8], c2[8];
#pragma unroll
        for (int i = 0; i < 8; ++i) {
            c1[i] = fv[i] * LOG2E;
            c2[i] = fv[i] * (ALPHA * LOG2E);
        }
        f16x8 av0, av1;
#pragma unroll
        for (int i = 0; i < 8; ++i) {
            float t0 = fmaxf(A0 + c1[i], B0 + c2[i]);
            t0 = ((mb0 >> i) & 1u) ? t0 : -1e30f;
            av0[i] = (_Float16)exp2f(t0);
            float t1 = fmaxf(A1 + c1[i], B1 + c2[i]);
            t1 = ((mb1 >> i) & 1u) ? t1 : -1e30f;
            av1[i] = (_Float16)exp2f(t1);
        }
        al0 = __builtin_amdgcn_mfma_f32_16x16x32_f16(av0, ones, al0, 0, 0, 0);
        al1 = __builtin_amdgcn_mfma_f32_16x16x32_f16(av1, ones, al1, 0, 0, 0);
        const _Float16* bb = whb + jb;
#pragma unroll
        for (int t4 = 0; t4 < 4; ++t4) {
            f16x8 bv = *(const f16x8*)(bb + (size_t)(16 * t4 + rl) * NN);
            a0[t4] = __builtin_amdgcn_mfma_f32_16x16x32_f16(av0, bv, a0[t4], 0, 0, 0);
            a1[t4] = __builtin_amdgcn_mfma_f32_16x16x32_f16(av1, bv, a1[t4], 0, 0, 0);
        }
    }
    // ---- pass rt=0 ----
#pragma unroll
    for (int t4 = 0; t4 < 4; ++t4)
#pragma unroll
        for (int i = 0; i < 4; ++i) red[w][t4 * 4 + i][l] = a0[t4][i];
    if (rl == 0) {
#pragma unroll
        for (int i = 0; i < 4; ++i) lred[w][4 * g + i] = al0[i];
    }
    __syncthreads();
    if (w < 4) {
#pragma unroll
        for (int i = 0; i < 4; ++i) {
            float v = 0.f, L = 0.f;
#pragma unroll
            for (int cc = 0; cc < 16; ++cc) { v += red[cc][w * 4 + i][l]; L += lred[cc][4 * g + i]; }
            float o = v * __builtin_amdgcn_rcpf(L);
            o = o > 0.f ? o : __expf(o) - 1.f;   // ELU
            int r = row0 + 4 * g + i;
            int d = 16 * w + rl;
            if (MODE == 0) ((_Float16*)outp)[(size_t)r * (NH * DH) + h * DH + d] = (_Float16)o;
            else           ((float*)outp)[((size_t)h * NN + r) * DH + d] = o;
        }
    }
    __syncthreads();
    // ---- pass rt=1 ----
#pragma unroll
    for (int t4 = 0; t4 < 4; ++t4)
#pragma unroll
        for (int i = 0; i < 4; ++i) red[w][t4 * 4 + i][l] = a1[t4][i];
    if (rl == 0) {
#pragma unroll
        for (int i = 0; i < 4; ++i) lred[w][4 * g + i] = al1[i];
    }
    __syncthreads();
    if (w < 4) {
#pragma unroll
        for (int i = 0; i < 4; ++i) {
            float v = 0.f, L = 0.f;
#pragma unroll
            for (int cc = 0; cc < 16; ++cc) { v += red[cc][w * 4 + i][l]; L += lred[cc][4 * g + i]; }
            float o = v * __builtin_amdgcn_rcpf(L);
            o = o > 0.f ? o : __expf(o) - 1.f;
            int r = row0 + 16 + 4 * g + i;
            int d = 16 * w + rl;
            if (MODE == 0) ((_Float16*)outp)[(size_t)r * (NH * DH) + h * DH + d] = (_Float16)o;
            else           ((float*)outp)[((size_t)h * NN + r) * DH + d] = o;
        }
    }
}

// ---- layer1 Wh via MFMA + fused fs/fd/fdmax; writes whT1 ----
__global__ __launch_bounds__(256) void k_l1wh(const _Float16* __restrict__ h16,
        const _Float16* __restrict__ w1T, const float* __restrict__ a1,
        _Float16* __restrict__ whT, float* __restrict__ fs, float* __restrict__ fd,
        float* __restrict__ fdm) {
    __shared__ float red[4][16][64];
    __shared__ _Float16 lt[16][64];
    int h = blockIdx.x >> 8;
    int row0 = (blockIdx.x & 255) << 4;
    int tid = threadIdx.x;
    int l = tid & 63, w = tid >> 6;
    int rl = l & 15, g = l >> 4;
    f32x4 acc[4] = {{0,0,0,0},{0,0,0,0},{0,0,0,0},{0,0,0,0}};
    const _Float16* ap = h16 + (size_t)(row0 + rl) * (NH * DH) + w * 64;
    const _Float16* bp = w1T + ((size_t)h * DH << 8) + w * 64;
#pragma unroll
    for (int j = 0; j < 2; ++j) {
        int fb = j * 32 + 8 * g;
        f16x8 avv = *(const f16x8*)(ap + fb);
#pragma unroll
        for (int t4 = 0; t4 < 4; ++t4) {
            f16x8 bv = *(const f16x8*)(bp + ((size_t)(16 * t4 + rl) << 8) + fb);
            acc[t4] = __builtin_amdgcn_mfma_f32_16x16x32_f16(avv, bv, acc[t4], 0, 0, 0);
        }
    }
#pragma unroll
    for (int t4 = 0; t4 < 4; ++t4)
#pragma unroll
        for (int i = 0; i < 4; ++i) red[w][t4 * 4 + i][l] = acc[t4][i];
    __syncthreads();
#pragma unroll
    for (int i = 0; i < 4; ++i) {
        float v = red[0][w * 4 + i][l] + red[1][w * 4 + i][l]
                + red[2][w * 4 + i][l] + red[3][w * 4 + i][l];
        lt[4 * g + i][16 * w + rl] = (_Float16)v;
    }
    __syncthreads();
    int d = tid & 63, rb = tid >> 6;
    f16x4 o;
#pragma unroll
    for (int j = 0; j < 4; ++j) o[j] = lt[rb * 4 + j][d];
    *(f16x4*)(whT + (size_t)(h * DH + d) * NN + row0 + rb * 4) = o;
    // fused fs/fd/fdmax: wave rb handles nodes rb*4..rb*4+3, lane = d
    float as_ = a1[h * 2 * DH + d], ad_ = a1[h * 2 * DH + DH + d];
    float svj[4], dvj[4];
#pragma unroll
    for (int j = 0; j < 4; ++j) {
        float wv = (float)lt[rb * 4 + j][d];
        svj[j] = wv * as_;
        dvj[j] = wv * ad_;
    }
#pragma unroll
    for (int off = 1; off <= 32; off <<= 1) {
#pragma unroll
        for (int j = 0; j < 4; ++j) {
            svj[j] += __shfl_xor(svj[j], off);
            dvj[j] += __shfl_xor(dvj[j], off);
        }
    }
    if (d == 0) {
        float m4 = -3e38f;
#pragma unroll
        for (int j = 0; j < 4; ++j) {
            fs[h * NN + row0 + rb * 4 + j] = svj[j];
            fd[h * NN + row0 + rb * 4 + j] = dvj[j];
            m4 = fmaxf(m4, dvj[j]);
        }
        atomicMaxF(fdm + h, m4);
    }
}

// ---- combine heads: mean over h ----
__global__ void k_comb(const float* __restrict__ out1, float* __restrict__ out) {
    int t = blockIdx.x * 256 + threadIdx.x;
    const int S = NN * DH;
    out[t] = 0.25f * (out1[t] + out1[t + S] + out1[t + 2 * S] + out1[t + 3 * S]);
}

extern "C" void kernel_launch(void* const* d_in, const int* in_sizes, int n_in,
                              void* d_out, int out_size, void* d_ws, size_t ws_size,
                              hipStream_t stream) {
    const float* x  = (const float*)d_in[0];
    const int* adj  = (const int*)d_in[1];
    const float* W0 = (const float*)d_in[2];
    const float* a0 = (const float*)d_in[3];
    const float* W1 = (const float*)d_in[4];
    const float* a1 = (const float*)d_in[5];
    float* out = (float*)d_out;
    char* ws = (char*)d_ws;

    unsigned int* bits = (unsigned int*)(ws);                          // 2MB
    _Float16* whT0 = (_Float16*)(ws + (2ull << 20));                   // 2MB
    _Float16* h16  = (_Float16*)(ws + (4ull << 20));                   // 2MB
    _Float16* w1T  = (_Float16*)(ws + (6ull << 20));                   // 128KB
    _Float16* whT1 = (_Float16*)(ws + (6ull << 20) + (256ull << 10));  // 2MB
    float* fs0  = (float*)(ws + (9ull << 20));
    float* fd0  = fs0 + NH * NN;
    float* fs1  = fd0 + NH * NN;
    float* fd1  = fs1 + NH * NN;
    float* fdm0 = fd1 + NH * NN;   // 8 floats
    float* fdm1 = fdm0 + 8;
    float* out1 = (float*)(ws + (10ull << 20));                        // 4MB

    k_pack<<<(NN / 256) * NN, 256, 0, stream>>>(adj, bits, fdm0);
    k_w1t<<<(NH * NH * DH * DH) / 256, 256, 0, stream>>>(W1, w1T);
    k_l0wh<<<NN / 16, 256, 0, stream>>>(x, W0, a0, whT0, fs0, fd0, fdm0);
    k_attn<0><<<NH * (NN / 32), 1024, 0, stream>>>(fs0, fd0, fdm0, whT0, bits, h16);
    k_l1wh<<<NH * (NN / 16), 256, 0, stream>>>(h16, w1T, a1, whT1, fs1, fd1, fdm1);
    k_attn<1><<<NH * (NN / 32), 1024, 0, stream>>>(fs1, fd1, fdm1, whT1, bits, out1);
    k_comb<<<(NN * DH) / 256, 256, 0, stream>>>(out1, out);
}

// Round 4
// 179.812 us; speedup vs baseline: 1.9705x; 1.9705x over previous
//
#include <hip/hip_runtime.h>
#include <hip/hip_fp16.h>
#include <math.h>

#define NN 4096
#define FIN 20
#define NH 4
#define DH 64
#define ALPHA 0.2f
#define LOG2E 1.4426950408889634f

typedef _Float16 f16x8 __attribute__((ext_vector_type(8)));
typedef _Float16 f16x4 __attribute__((ext_vector_type(4)));
typedef float f32x4 __attribute__((ext_vector_type(4)));

__device__ inline void atomicMaxF(float* a, float v) {
    if (v >= 0.f) atomicMax((int*)a, __float_as_int(v));
    else atomicMin((unsigned int*)a, __float_as_uint(v));
}

__device__ inline void gload_lds16(const void* gsrc, void* ldsbase) {
    __builtin_amdgcn_global_load_lds(
        (const __attribute__((address_space(1))) void*)gsrc,
        (__attribute__((address_space(3))) void*)ldsbase, 16, 0, 0);
}

// ---- pack adjacency into bitmask (8 ints -> 1 byte per thread) + init fdm ----
__global__ __launch_bounds__(256) void k_pack(const int* __restrict__ adj,
        unsigned char* __restrict__ bits, float* __restrict__ fdm) {
    int t = blockIdx.x * 256 + threadIdx.x;
    if (blockIdx.x == 0 && threadIdx.x < 16) fdm[threadIdx.x] = -3e38f;
    const int4* p = (const int4*)(adj + (size_t)t * 8);
    int4 a = p[0], b = p[1];
    unsigned int byte = 0;
    byte |= (a.x > 0) << 0; byte |= (a.y > 0) << 1;
    byte |= (a.z > 0) << 2; byte |= (a.w > 0) << 3;
    byte |= (b.x > 0) << 4; byte |= (b.y > 0) << 5;
    byte |= (b.z > 0) << 6; byte |= (b.w > 0) << 7;
    bits[t] = (unsigned char)byte;
}

// ---- layer0 Wh -> whT (f16, [h][d][n]) + fused fs/fd/fdmax ----
__global__ __launch_bounds__(256) void k_l0wh(const float* __restrict__ x,
        const float* __restrict__ W0, const float* __restrict__ a0,
        _Float16* __restrict__ whT, float* __restrict__ fs, float* __restrict__ fd,
        float* __restrict__ fdm) {
    __shared__ float xs[16 * FIN];
    int n0 = blockIdx.x * 16;
    int tid = threadIdx.x;
    for (int i = tid; i < 16 * FIN; i += 256) xs[i] = x[n0 * FIN + i];
    __syncthreads();
    int h = tid >> 6, d = tid & 63;
    float w0r[FIN];
#pragma unroll
    for (int f = 0; f < FIN; ++f) w0r[f] = W0[(h * FIN + f) * DH + d];
    float asrc = a0[h * 2 * DH + d];
    float adst = a0[h * 2 * DH + DH + d];
    float mdv = -3e38f;
    f16x8 wv[2];
#pragma unroll
    for (int n = 0; n < 16; ++n) {
        float wh = 0.f;
#pragma unroll
        for (int f = 0; f < FIN; ++f) wh = fmaf(xs[n * FIN + f], w0r[f], wh);
        wv[n >> 3][n & 7] = (_Float16)wh;
        float sv = wh * asrc, dv = wh * adst;
#pragma unroll
        for (int off = 1; off <= 32; off <<= 1) {
            sv += __shfl_xor(sv, off);
            dv += __shfl_xor(dv, off);
        }
        mdv = fmaxf(mdv, dv);
        if (d == 0) { fs[h * NN + n0 + n] = sv; fd[h * NN + n0 + n] = dv; }
    }
    if (d == 0) atomicMaxF(fdm + h, mdv);
    _Float16* dst = whT + ((size_t)(h * DH + d) * NN + n0);
    *(f16x8*)(dst) = wv[0];
    *(f16x8*)(dst + 8) = wv[1];
}

// ---- W1 [h][256][64] -> w1T [h][64][256] f16 (read-coalesced) ----
__global__ void k_w1t(const float* __restrict__ W1, _Float16* __restrict__ w1T) {
    int u = blockIdx.x * 256 + threadIdx.x;     // 0..65535
    int h = u >> 14, f = (u >> 6) & 255, d = u & 63;
    w1T[((size_t)(h * DH + d) << 8) + f] = (_Float16)W1[u];
}

// ---- attention: flash-style, B staged in LDS, 8 waves = 2 row-tiles x 4 col-quarters
// MODE 0: write h16 [n][H*DH] f16   MODE 1: write out1 [h][n][DH] f32
template<int MODE>
__global__ __launch_bounds__(512, 4) void k_attn(const float* __restrict__ fs,
        const float* __restrict__ fd, const float* __restrict__ fdmax,
        const _Float16* __restrict__ whT, const unsigned char* __restrict__ bits,
        void* __restrict__ outp) {
    // smem: stage 2 x 16KB (overlaid by red 32KB in epilogue) + lred 512B
    __shared__ __align__(16) char smem[33280];
    const int h = blockIdx.x >> 7;
    const int row0 = (blockIdx.x & 127) << 5;   // 32 rows per block
    const int tid = threadIdx.x;
    const int l = tid & 63, w = tid >> 6;       // 8 waves
    const int rl = l & 15, g = l >> 4;
    const int q = w & 3, rt = w >> 2;           // col-quarter, row-tile
    const int row = row0 + 16 * rt + rl;
    const float fsr = fs[h * NN + row];
    const float fm = fdmax[h];
    const float su = fsr + fm;
    const float m0 = fmaxf(su, ALPHA * su);     // upper bound of row max
    const float A0 = (fsr - m0) * LOG2E;
    const float B0 = (ALPHA * fsr - m0) * LOG2E;
    const float* fdp = fd + h * NN;
    const unsigned char* brow = bits + (size_t)row * (NN / 8);
    const _Float16* whb = whT + (size_t)h * DH * NN;

    f32x4 acc[4] = {{0,0,0,0},{0,0,0,0},{0,0,0,0},{0,0,0,0}};
    f32x4 al = {0,0,0,0};
    f16x8 ones;
#pragma unroll
    for (int i = 0; i < 8; ++i) ones[i] = (_Float16)1.0f;

    // ---- prologue: stage tile 0 ----
#pragma unroll
    for (int r = 0; r < 2; ++r) {
        int tp = r * 512 + tid;
        int d = tp >> 4, c = tp & 15;
        const _Float16* src = whb + (size_t)d * NN + 8 * (c ^ (d & 7));
        gload_lds16(src, smem + r * 8192 + w * 1024);
    }
    __syncthreads();

    const int NT = NN / 128;                    // 32 tiles
    for (int t = 0; t < NT; ++t) {
        // prefetch next tile into other buffer
        if (t + 1 < NT) {
            int jn = (t + 1) << 7;
            char* buf1 = smem + ((t + 1) & 1) * 16384;
#pragma unroll
            for (int r = 0; r < 2; ++r) {
                int tp = r * 512 + tid;
                int d = tp >> 4, c = tp & 15;
                const _Float16* src = whb + (size_t)d * NN + jn + 8 * (c ^ (d & 7));
                gload_lds16(src, buf1 + r * 8192 + w * 1024);
            }
        }
        // compute on current buffer
        const char* buf = smem + (t & 1) * 16384;
        const int jt = t << 7;
        const int jq = jt + (q << 5);           // this wave's 32-col chunk
        const int jl = jq + (g << 3);           // this lane's 8 cols
        float4 fa = *(const float4*)(fdp + jl);
        float4 fb = *(const float4*)(fdp + jl + 4);
        unsigned int mb = *(const unsigned int*)(brow + (jq >> 3));
        float fv[8] = {fa.x, fa.y, fa.z, fa.w, fb.x, fb.y, fb.z, fb.w};
        f16x8 av;
        const int sh = g << 3;
#pragma unroll
        for (int i = 0; i < 8; ++i) {
            float tv = fmaxf(fmaf(fv[i], LOG2E, A0), fmaf(fv[i], ALPHA * LOG2E, B0));
            tv = ((mb >> (sh + i)) & 1u) ? tv : -1e30f;
            av[i] = (_Float16)exp2f(tv);
        }
        al = __builtin_amdgcn_mfma_f32_16x16x32_f16(av, ones, al, 0, 0, 0);
        const int cb = ((q << 6) | (g << 4)) ^ ((rl & 7) << 4);   // swizzled col-byte
        const int rb = rl * 256 + cb;
#pragma unroll
        for (int t4 = 0; t4 < 4; ++t4) {
            f16x8 bv = *(const f16x8*)(buf + t4 * 4096 + rb);
            acc[t4] = __builtin_amdgcn_mfma_f32_16x16x32_f16(av, bv, acc[t4], 0, 0, 0);
        }
        __syncthreads();
    }

    // ---- epilogue: 4-way cross-quarter reduce in LDS (overlays stage) ----
    float* red = (float*)smem;                  // [2][4][16][64]
    float* lred = (float*)(smem + 32768);       // [2][4][16]
#pragma unroll
    for (int t4 = 0; t4 < 4; ++t4)
#pragma unroll
        for (int i = 0; i < 4; ++i)
            red[(((rt * 4 + q) * 16) + 4 * g + i) * 64 + 16 * t4 + rl] = acc[t4][i];
    if (rl == 0) {
#pragma unroll
        for (int i = 0; i < 4; ++i) lred[(rt * 4 + q) * 16 + 4 * g + i] = al[i];
    }
    __syncthreads();
    // wave w finalizes rows [4w, 4w+4), lane l = d
#pragma unroll
    for (int j = 0; j < 4; ++j) {
        int R = 4 * w + j;
        int rt2 = R >> 4, rr = R & 15;
        float v = 0.f, L = 0.f;
#pragma unroll
        for (int qq = 0; qq < 4; ++qq) {
            v += red[((rt2 * 4 + qq) * 16 + rr) * 64 + l];
            L += lred[(rt2 * 4 + qq) * 16 + rr];
        }
        float o = v * __builtin_amdgcn_rcpf(L);
        o = o > 0.f ? o : __expf(o) - 1.f;      // ELU
        int Rg = row0 + R;
        if (MODE == 0) ((_Float16*)outp)[(size_t)Rg * (NH * DH) + h * DH + l] = (_Float16)o;
        else           ((float*)outp)[((size_t)h * NN + Rg) * DH + l] = o;
    }
}

// ---- layer1 Wh via MFMA + fused fs/fd/fdmax; writes whT1 ----
__global__ __launch_bounds__(256) void k_l1wh(const _Float16* __restrict__ h16,
        const _Float16* __restrict__ w1T, const float* __restrict__ a1,
        _Float16* __restrict__ whT, float* __restrict__ fs, float* __restrict__ fd,
        float* __restrict__ fdm) {
    __shared__ float red[4][16][64];
    __shared__ _Float16 lt[16][64];
    int h = blockIdx.x >> 8;
    int row0 = (blockIdx.x & 255) << 4;
    int tid = threadIdx.x;
    int l = tid & 63, w = tid >> 6;
    int rl = l & 15, g = l >> 4;
    f32x4 acc[4] = {{0,0,0,0},{0,0,0,0},{0,0,0,0},{0,0,0,0}};
    const _Float16* ap = h16 + (size_t)(row0 + rl) * (NH * DH) + w * 64;
    const _Float16* bp = w1T + ((size_t)h * DH << 8) + w * 64;
#pragma unroll
    for (int j = 0; j < 2; ++j) {
        int fb = j * 32 + 8 * g;
        f16x8 avv = *(const f16x8*)(ap + fb);
#pragma unroll
        for (int t4 = 0; t4 < 4; ++t4) {
            f16x8 bv = *(const f16x8*)(bp + ((size_t)(16 * t4 + rl) << 8) + fb);
            acc[t4] = __builtin_amdgcn_mfma_f32_16x16x32_f16(avv, bv, acc[t4], 0, 0, 0);
        }
    }
#pragma unroll
    for (int t4 = 0; t4 < 4; ++t4)
#pragma unroll
        for (int i = 0; i < 4; ++i) red[w][t4 * 4 + i][l] = acc[t4][i];
    __syncthreads();
#pragma unroll
    for (int i = 0; i < 4; ++i) {
        float v = red[0][w * 4 + i][l] + red[1][w * 4 + i][l]
                + red[2][w * 4 + i][l] + red[3][w * 4 + i][l];
        lt[4 * g + i][16 * w + rl] = (_Float16)v;
    }
    __syncthreads();
    int d = tid & 63, rb = tid >> 6;
    f16x4 o;
#pragma unroll
    for (int j = 0; j < 4; ++j) o[j] = lt[rb * 4 + j][d];
    *(f16x4*)(whT + (size_t)(h * DH + d) * NN + row0 + rb * 4) = o;
    // fused fs/fd/fdmax
    float as_ = a1[h * 2 * DH + d], ad_ = a1[h * 2 * DH + DH + d];
    float svj[4], dvj[4];
#pragma unroll
    for (int j = 0; j < 4; ++j) {
        float wv = (float)lt[rb * 4 + j][d];
        svj[j] = wv * as_;
        dvj[j] = wv * ad_;
    }
#pragma unroll
    for (int off = 1; off <= 32; off <<= 1) {
#pragma unroll
        for (int j = 0; j < 4; ++j) {
            svj[j] += __shfl_xor(svj[j], off);
            dvj[j] += __shfl_xor(dvj[j], off);
        }
    }
    if (d == 0) {
        float m4 = -3e38f;
#pragma unroll
        for (int j = 0; j < 4; ++j) {
            fs[h * NN + row0 + rb * 4 + j] = svj[j];
            fd[h * NN + row0 + rb * 4 + j] = dvj[j];
            m4 = fmaxf(m4, dvj[j]);
        }
        atomicMaxF(fdm + h, m4);
    }
}

// ---- combine heads: mean over h ----
__global__ void k_comb(const float* __restrict__ out1, float* __restrict__ out) {
    int t = blockIdx.x * 256 + threadIdx.x;
    const int S = NN * DH;
    out[t] = 0.25f * (out1[t] + out1[t + S] + out1[t + 2 * S] + out1[t + 3 * S]);
}

extern "C" void kernel_launch(void* const* d_in, const int* in_sizes, int n_in,
                              void* d_out, int out_size, void* d_ws, size_t ws_size,
                              hipStream_t stream) {
    const float* x  = (const float*)d_in[0];
    const int* adj  = (const int*)d_in[1];
    const float* W0 = (const float*)d_in[2];
    const float* a0 = (const float*)d_in[3];
    const float* W1 = (const float*)d_in[4];
    const float* a1 = (const float*)d_in[5];
    float* out = (float*)d_out;
    char* ws = (char*)d_ws;

    unsigned char* bits = (unsigned char*)(ws);                        // 2MB
    _Float16* whT0 = (_Float16*)(ws + (2ull << 20));                   // 2MB
    _Float16* h16  = (_Float16*)(ws + (4ull << 20));                   // 2MB
    _Float16* w1T  = (_Float16*)(ws + (6ull << 20));                   // 128KB
    _Float16* whT1 = (_Float16*)(ws + (6ull << 20) + (256ull << 10));  // 2MB
    float* fs0  = (float*)(ws + (9ull << 20));
    float* fd0  = fs0 + NH * NN;
    float* fs1  = fd0 + NH * NN;
    float* fd1  = fs1 + NH * NN;
    float* fdm0 = fd1 + NH * NN;   // 8 floats
    float* fdm1 = fdm0 + 8;
    float* out1 = (float*)(ws + (10ull << 20));                        // 4MB

    k_pack<<<NN * NN / 8 / 256, 256, 0, stream>>>(adj, bits, fdm0);
    k_w1t<<<(NH * NH * DH * DH) / 256, 256, 0, stream>>>(W1, w1T);
    k_l0wh<<<NN / 16, 256, 0, stream>>>(x, W0, a0, whT0, fs0, fd0, fdm0);
    k_attn<0><<<NH * (NN / 32), 512, 0, stream>>>(fs0, fd0, fdm0, whT0, bits, h16);
    k_l1wh<<<NH * (NN / 16), 256, 0, stream>>>(h16, w1T, a1, whT1, fs1, fd1, fdm1);
    k_attn<1><<<NH * (NN / 32), 512, 0, stream>>>(fs1, fd1, fdm1, whT1, bits, out1);
    k_comb<<<(NN * DH) / 256, 256, 0, stream>>>(out1, out);
}

// Round 5
// 141.652 us; speedup vs baseline: 2.5013x; 1.2694x over previous
//
#include <hip/hip_runtime.h>
#include <hip/hip_fp16.h>
#include <math.h>

#define NN 4096
#define FIN 20
#define NH 4
#define DH 64
#define ALPHA 0.2f
#define LOG2E 1.4426950408889634f

typedef _Float16 f16x8 __attribute__((ext_vector_type(8)));
typedef _Float16 f16x4 __attribute__((ext_vector_type(4)));
typedef float f32x4 __attribute__((ext_vector_type(4)));

__device__ inline void gload_lds16(const void* gsrc, void* ldsbase) {
    __builtin_amdgcn_global_load_lds(
        (const __attribute__((address_space(1))) void*)gsrc,
        (__attribute__((address_space(3))) void*)ldsbase, 16, 0, 0);
}

// ---- pack adjacency into bitmask (8 ints -> 1 byte per thread) ----
__global__ __launch_bounds__(256) void k_pack(const int* __restrict__ adj,
        unsigned char* __restrict__ bits) {
    int t = blockIdx.x * 256 + threadIdx.x;
    const int4* p = (const int4*)(adj + (size_t)t * 8);
    int4 a = p[0], b = p[1];
    unsigned int byte = 0;
    byte |= (a.x > 0) << 0; byte |= (a.y > 0) << 1;
    byte |= (a.z > 0) << 2; byte |= (a.w > 0) << 3;
    byte |= (b.x > 0) << 4; byte |= (b.y > 0) << 5;
    byte |= (b.z > 0) << 6; byte |= (b.w > 0) << 7;
    bits[t] = (unsigned char)byte;
}

// ---- layer0 Wh -> whT (f16, [h][d][n]) + fs/fd (no atomics) ----
__global__ __launch_bounds__(256) void k_l0wh(const float* __restrict__ x,
        const float* __restrict__ W0, const float* __restrict__ a0,
        _Float16* __restrict__ whT, float* __restrict__ fs, float* __restrict__ fd) {
    __shared__ float xs[16 * FIN];
    int n0 = blockIdx.x * 16;
    int tid = threadIdx.x;
    for (int i = tid; i < 16 * FIN; i += 256) xs[i] = x[n0 * FIN + i];
    __syncthreads();
    int h = tid >> 6, d = tid & 63;
    float w0r[FIN];
#pragma unroll
    for (int f = 0; f < FIN; ++f) w0r[f] = W0[(h * FIN + f) * DH + d];
    float asrc = a0[h * 2 * DH + d];
    float adst = a0[h * 2 * DH + DH + d];
    f16x8 wv[2];
#pragma unroll
    for (int n = 0; n < 16; ++n) {
        float wh = 0.f;
#pragma unroll
        for (int f = 0; f < FIN; ++f) wh = fmaf(xs[n * FIN + f], w0r[f], wh);
        wv[n >> 3][n & 7] = (_Float16)wh;
        float sv = wh * asrc, dv = wh * adst;
#pragma unroll
        for (int off = 1; off <= 32; off <<= 1) {
            sv += __shfl_xor(sv, off);
            dv += __shfl_xor(dv, off);
        }
        if (d == 0) { fs[h * NN + n0 + n] = sv; fd[h * NN + n0 + n] = dv; }
    }
    _Float16* dst = whT + ((size_t)(h * DH + d) * NN + n0);
    *(f16x8*)(dst) = wv[0];
    *(f16x8*)(dst + 8) = wv[1];
}

// ---- per-head max of fd (4 blocks, no atomics) ----
__global__ __launch_bounds__(256) void k_fdmax(const float* __restrict__ fd,
        float* __restrict__ fdm) {
    int h = blockIdx.x, tid = threadIdx.x;
    float m = -3e38f;
    for (int i = tid; i < NN; i += 256) m = fmaxf(m, fd[h * NN + i]);
#pragma unroll
    for (int off = 1; off <= 32; off <<= 1) m = fmaxf(m, __shfl_xor(m, off));
    __shared__ float mx[4];
    if ((tid & 63) == 0) mx[tid >> 6] = m;
    __syncthreads();
    if (tid == 0) fdm[h] = fmaxf(fmaxf(mx[0], mx[1]), fmaxf(mx[2], mx[3]));
}

// ---- W1 [h][256][64] -> w1T [h][64][256] f16 (read-coalesced) ----
__global__ void k_w1t(const float* __restrict__ W1, _Float16* __restrict__ w1T) {
    int u = blockIdx.x * 256 + threadIdx.x;     // 0..65535
    int h = u >> 14, f = (u >> 6) & 255, d = u & 63;
    w1T[((size_t)(h * DH + d) << 8) + f] = (_Float16)W1[u];
}

// ---- attention partial: 32 rows x 2048 cols per block, LDS-staged B ----
// writes pv[ch][h][n][64] f32 and pl[ch][h][n] f32
__global__ __launch_bounds__(512, 4) void k_attn(const float* __restrict__ fs,
        const float* __restrict__ fd, const float* __restrict__ fdmax,
        const _Float16* __restrict__ whT, const unsigned char* __restrict__ bits,
        float* __restrict__ pv, float* __restrict__ pl) {
    __shared__ __align__(16) char smem[33280];
    const int ch = blockIdx.x & 1;              // column half
    const int row0 = ((blockIdx.x >> 1) & 127) << 5;
    const int h = blockIdx.x >> 8;
    const int cb0 = ch << 11;                   // 2048-col base
    const int tid = threadIdx.x;
    const int l = tid & 63, w = tid >> 6;       // 8 waves
    const int rl = l & 15, g = l >> 4;
    const int q = w & 3, rt = w >> 2;           // col-quarter, row-tile
    const int row = row0 + 16 * rt + rl;
    const float fsr = fs[h * NN + row];
    const float fm = fdmax[h];
    const float su = fsr + fm;
    const float m0 = fmaxf(su, ALPHA * su);     // upper bound of row max
    const float A0 = (fsr - m0) * LOG2E;
    const float B0 = (ALPHA * fsr - m0) * LOG2E;
    const float* fdp = fd + h * NN;
    const unsigned char* brow = bits + (size_t)row * (NN / 8);
    const _Float16* whb = whT + (size_t)h * DH * NN;

    f32x4 acc[4] = {{0,0,0,0},{0,0,0,0},{0,0,0,0},{0,0,0,0}};
    f32x4 al = {0,0,0,0};
    f16x8 ones;
#pragma unroll
    for (int i = 0; i < 8; ++i) ones[i] = (_Float16)1.0f;

    // ---- prologue: stage tile 0 of this half ----
#pragma unroll
    for (int r = 0; r < 2; ++r) {
        int tp = r * 512 + tid;
        int d = tp >> 4, c = tp & 15;
        const _Float16* src = whb + (size_t)d * NN + cb0 + 8 * (c ^ (d & 7));
        gload_lds16(src, smem + r * 8192 + w * 1024);
    }
    __syncthreads();

    const int NT = 16;                          // 16 tiles x 128 cols = 2048
    for (int t = 0; t < NT; ++t) {
        if (t + 1 < NT) {
            int jn = cb0 + ((t + 1) << 7);
            char* buf1 = smem + ((t + 1) & 1) * 16384;
#pragma unroll
            for (int r = 0; r < 2; ++r) {
                int tp = r * 512 + tid;
                int d = tp >> 4, c = tp & 15;
                const _Float16* src = whb + (size_t)d * NN + jn + 8 * (c ^ (d & 7));
                gload_lds16(src, buf1 + r * 8192 + w * 1024);
            }
        }
        const char* buf = smem + (t & 1) * 16384;
        const int jq = cb0 + (t << 7) + (q << 5);
        const int jl = jq + (g << 3);
        float4 fa = *(const float4*)(fdp + jl);
        float4 fb = *(const float4*)(fdp + jl + 4);
        unsigned int mb = *(const unsigned int*)(brow + (jq >> 3));
        float fv[8] = {fa.x, fa.y, fa.z, fa.w, fb.x, fb.y, fb.z, fb.w};
        f16x8 av;
        const int sh = g << 3;
#pragma unroll
        for (int i = 0; i < 8; ++i) {
            float tv = fmaxf(fmaf(fv[i], LOG2E, A0), fmaf(fv[i], ALPHA * LOG2E, B0));
            tv = ((mb >> (sh + i)) & 1u) ? tv : -1e30f;
            av[i] = (_Float16)exp2f(tv);
        }
        al = __builtin_amdgcn_mfma_f32_16x16x32_f16(av, ones, al, 0, 0, 0);
        const int cb = ((q << 6) | (g << 4)) ^ ((rl & 7) << 4);   // swizzled col-byte
        const int rb = rl * 256 + cb;
#pragma unroll
        for (int t4 = 0; t4 < 4; ++t4) {
            f16x8 bv = *(const f16x8*)(buf + t4 * 4096 + rb);
            acc[t4] = __builtin_amdgcn_mfma_f32_16x16x32_f16(av, bv, acc[t4], 0, 0, 0);
        }
        __syncthreads();
    }

    // ---- epilogue: 4-way cross-quarter reduce in LDS, write partials ----
    float* red = (float*)smem;                  // [2][4][16][64]
    float* lred = (float*)(smem + 32768);       // [2][4][16]
#pragma unroll
    for (int t4 = 0; t4 < 4; ++t4)
#pragma unroll
        for (int i = 0; i < 4; ++i)
            red[(((rt * 4 + q) * 16) + 4 * g + i) * 64 + 16 * t4 + rl] = acc[t4][i];
    if (rl == 0) {
#pragma unroll
        for (int i = 0; i < 4; ++i) lred[(rt * 4 + q) * 16 + 4 * g + i] = al[i];
    }
    __syncthreads();
#pragma unroll
    for (int j = 0; j < 4; ++j) {
        int R = 4 * w + j;
        int rt2 = R >> 4, rr = R & 15;
        float v = 0.f, L = 0.f;
#pragma unroll
        for (int qq = 0; qq < 4; ++qq) {
            v += red[((rt2 * 4 + qq) * 16 + rr) * 64 + l];
            L += lred[(rt2 * 4 + qq) * 16 + rr];
        }
        int Rg = row0 + R;
        pv[(((size_t)(ch * NH + h) * NN) + Rg) * 64 + l] = v;
        if (l == 0) pl[(size_t)(ch * NH + h) * NN + Rg] = L;
    }
}

// ---- merge halves; MODE 0 -> h16 [n][H*DH] f16 ; MODE 1 -> head-mean out f32 ----
template<int MODE>
__global__ __launch_bounds__(256) void k_merge(const float* __restrict__ pv,
        const float* __restrict__ pl, void* __restrict__ outp) {
    int t = blockIdx.x * 256 + threadIdx.x;
    if (MODE == 0) {
        int d = t & 63, n = (t >> 6) & (NN - 1), h = t >> 18;
        float v = pv[((size_t)h * NN + n) * 64 + d] + pv[((size_t)(NH + h) * NN + n) * 64 + d];
        float L = pl[h * NN + n] + pl[NH * NN + h * NN + n];
        float o = v * __builtin_amdgcn_rcpf(L);
        o = o > 0.f ? o : __expf(o) - 1.f;
        ((_Float16*)outp)[(size_t)n * (NH * DH) + h * DH + d] = (_Float16)o;
    } else {
        int d = t & 63, n = t >> 6;
        float s = 0.f;
#pragma unroll
        for (int h = 0; h < NH; ++h) {
            float v = pv[((size_t)h * NN + n) * 64 + d] + pv[((size_t)(NH + h) * NN + n) * 64 + d];
            float L = pl[h * NN + n] + pl[NH * NN + h * NN + n];
            float o = v * __builtin_amdgcn_rcpf(L);
            s += o > 0.f ? o : __expf(o) - 1.f;
        }
        ((float*)outp)[t] = 0.25f * s;
    }
}

// ---- layer1 Wh via MFMA + fs/fd (no atomics); writes whT1 ----
__global__ __launch_bounds__(256) void k_l1wh(const _Float16* __restrict__ h16,
        const _Float16* __restrict__ w1T, const float* __restrict__ a1,
        _Float16* __restrict__ whT, float* __restrict__ fs, float* __restrict__ fd) {
    __shared__ float red[4][16][64];
    __shared__ _Float16 lt[16][64];
    int h = blockIdx.x >> 8;
    int row0 = (blockIdx.x & 255) << 4;
    int tid = threadIdx.x;
    int l = tid & 63, w = tid >> 6;
    int rl = l & 15, g = l >> 4;
    f32x4 acc[4] = {{0,0,0,0},{0,0,0,0},{0,0,0,0},{0,0,0,0}};
    const _Float16* ap = h16 + (size_t)(row0 + rl) * (NH * DH) + w * 64;
    const _Float16* bp = w1T + ((size_t)h * DH << 8) + w * 64;
#pragma unroll
    for (int j = 0; j < 2; ++j) {
        int fb = j * 32 + 8 * g;
        f16x8 avv = *(const f16x8*)(ap + fb);
#pragma unroll
        for (int t4 = 0; t4 < 4; ++t4) {
            f16x8 bv = *(const f16x8*)(bp + ((size_t)(16 * t4 + rl) << 8) + fb);
            acc[t4] = __builtin_amdgcn_mfma_f32_16x16x32_f16(avv, bv, acc[t4], 0, 0, 0);
        }
    }
#pragma unroll
    for (int t4 = 0; t4 < 4; ++t4)
#pragma unroll
        for (int i = 0; i < 4; ++i) red[w][t4 * 4 + i][l] = acc[t4][i];
    __syncthreads();
#pragma unroll
    for (int i = 0; i < 4; ++i) {
        float v = red[0][w * 4 + i][l] + red[1][w * 4 + i][l]
                + red[2][w * 4 + i][l] + red[3][w * 4 + i][l];
        lt[4 * g + i][16 * w + rl] = (_Float16)v;
    }
    __syncthreads();
    int d = tid & 63, rb = tid >> 6;
    f16x4 o;
#pragma unroll
    for (int j = 0; j < 4; ++j) o[j] = lt[rb * 4 + j][d];
    *(f16x4*)(whT + (size_t)(h * DH + d) * NN + row0 + rb * 4) = o;
    // fs/fd (no atomics)
    float as_ = a1[h * 2 * DH + d], ad_ = a1[h * 2 * DH + DH + d];
    float svj[4], dvj[4];
#pragma unroll
    for (int j = 0; j < 4; ++j) {
        float wv = (float)lt[rb * 4 + j][d];
        svj[j] = wv * as_;
        dvj[j] = wv * ad_;
    }
#pragma unroll
    for (int off = 1; off <= 32; off <<= 1) {
#pragma unroll
        for (int j = 0; j < 4; ++j) {
            svj[j] += __shfl_xor(svj[j], off);
            dvj[j] += __shfl_xor(dvj[j], off);
        }
    }
    if (d == 0) {
#pragma unroll
        for (int j = 0; j < 4; ++j) {
            fs[h * NN + row0 + rb * 4 + j] = svj[j];
            fd[h * NN + row0 + rb * 4 + j] = dvj[j];
        }
    }
}

extern "C" void kernel_launch(void* const* d_in, const int* in_sizes, int n_in,
                              void* d_out, int out_size, void* d_ws, size_t ws_size,
                              hipStream_t stream) {
    const float* x  = (const float*)d_in[0];
    const int* adj  = (const int*)d_in[1];
    const float* W0 = (const float*)d_in[2];
    const float* a0 = (const float*)d_in[3];
    const float* W1 = (const float*)d_in[4];
    const float* a1 = (const float*)d_in[5];
    float* out = (float*)d_out;
    char* ws = (char*)d_ws;

    unsigned char* bits = (unsigned char*)(ws);                        // 2MB
    _Float16* whT0 = (_Float16*)(ws + (2ull << 20));                   // 2MB
    _Float16* h16  = (_Float16*)(ws + (4ull << 20));                   // 2MB
    _Float16* w1T  = (_Float16*)(ws + (6ull << 20));                   // 128KB
    _Float16* whT1 = (_Float16*)(ws + (6ull << 20) + (256ull << 10));  // 2MB
    float* fs0  = (float*)(ws + (9ull << 20));
    float* fd0  = fs0 + NH * NN;
    float* fs1  = fd0 + NH * NN;
    float* fd1  = fs1 + NH * NN;
    float* fdm0 = fd1 + NH * NN;   // 8 floats
    float* fdm1 = fdm0 + 8;
    float* pv   = (float*)(ws + (10ull << 20));                        // 8MB
    float* pl   = (float*)(ws + (18ull << 20));                        // 128KB

    k_pack<<<NN * NN / 8 / 256, 256, 0, stream>>>(adj, bits);
    k_w1t<<<(NH * NH * DH * DH) / 256, 256, 0, stream>>>(W1, w1T);
    k_l0wh<<<NN / 16, 256, 0, stream>>>(x, W0, a0, whT0, fs0, fd0);
    k_fdmax<<<NH, 256, 0, stream>>>(fd0, fdm0);
    k_attn<<<2 * NH * (NN / 32), 512, 0, stream>>>(fs0, fd0, fdm0, whT0, bits, pv, pl);
    k_merge<0><<<(NH * NN * DH) / 256, 256, 0, stream>>>(pv, pl, h16);
    k_l1wh<<<NH * (NN / 16), 256, 0, stream>>>(h16, w1T, a1, whT1, fs1, fd1);
    k_fdmax<<<NH, 256, 0, stream>>>(fd1, fdm1);
    k_attn<<<2 * NH * (NN / 32), 512, 0, stream>>>(fs1, fd1, fdm1, whT1, bits, pv, pl);
    k_merge<1><<<(NN * DH) / 256, 256, 0, stream>>>(pv, pl, out);
}